// Round 11
// baseline (130.370 us; speedup 1.0000x reference)
//
#include <hip/hip_runtime.h>
#include <hip/hip_bf16.h>

#define B_   8
#define N_   512
#define IND  256
#define H_   4
#define PH   32
#define OD   128   // H_*PH
#define TI   2     // targets per block (attn)

typedef float v2f __attribute__((ext_vector_type(2)));

// leaky 0.4 * log2(e), and 0.6 * log2(e): logits in log2 domain -> v_exp_f32.
#define ATT_SCALE 0.5770780163555854f
#define DLR_SCALE 0.8656170245333781f

template <int PAT>
__device__ __forceinline__ float dpp_add(float x) {
    int yi = __builtin_amdgcn_mov_dpp(__float_as_int(x), PAT, 0xF, 0xF, true);
    return x + __int_as_float(yi);
}

__device__ __forceinline__ float fast_exp2(float x) {
#if __has_builtin(__builtin_amdgcn_exp2f)
    return __builtin_amdgcn_exp2f(x);
#else
    return exp2f(x);
#endif
}

// Packed fp32 FMA: d += a*b on both halves, ONE VOP3P instruction.
__device__ __forceinline__ void pk_fma(v2f& d, v2f a, v2f b) {
    asm("v_pk_fma_f32 %0, %1, %2, %0" : "+v"(d) : "v"(a), "v"(b));
}

// ---------------------------------------------------------------------------
// Kernel 1: xl = x@Wl + bl ; xr = x@Wr + br  plus pre-scaled rank-1 parts
//   dl[n,h] = 0.6*log2e * sum_c att[h,c]*xl[n,h,c]; dr likewise.
// grid 512, block 256; 8 rows per block. (unchanged, proven r5-r10)
// ---------------------------------------------------------------------------
__global__ __launch_bounds__(256, 2) void proj_kernel(
    const float* __restrict__ x,
    const float* __restrict__ Wl, const float* __restrict__ bl,
    const float* __restrict__ Wr, const float* __restrict__ br,
    const float* __restrict__ att,
    float* __restrict__ xl, float* __restrict__ xr,
    float* __restrict__ dl, float* __restrict__ dr)
{
    __shared__ float xs[8 * IND];
    const int t = threadIdx.x;
    const int row0 = blockIdx.x * 8;

    const float4* xp4 = (const float4*)(x + (size_t)row0 * IND);
    float4* xs4 = (float4*)xs;
    #pragma unroll
    for (int k = 0; k < 2; ++k)
        xs4[t + k * 256] = xp4[t + k * 256];
    __syncthreads();

    const int which = t >> 7;
    const int rg = (t >> 6) & 1;
    const int og = t & 63;
    const int o0 = og * 2;
    const int r0 = rg * 4;
    const float* W  = which ? Wr : Wl;
    const float* bb = which ? br : bl;

    float acc0[4], acc1[4];
    #pragma unroll
    for (int r = 0; r < 4; ++r) { acc0[r] = 0.f; acc1[r] = 0.f; }

    for (int k = 0; k < IND; k += 4) {
        float wf0[4], wf1[4];
        #pragma unroll
        for (int kk = 0; kk < 4; ++kk) {
            float2 wv = *(const float2*)(W + (size_t)(k + kk) * OD + o0);
            wf0[kk] = wv.x;
            wf1[kk] = wv.y;
        }
        float xv[4][4];
        #pragma unroll
        for (int r = 0; r < 4; ++r)
            *(float4*)(xv[r]) = *(const float4*)(&xs[(r0 + r) * IND + k]);
        #pragma unroll
        for (int kk = 0; kk < 4; ++kk)
            #pragma unroll
            for (int r = 0; r < 4; ++r) {
                acc0[r] = fmaf(xv[r][kk], wf0[kk], acc0[r]);
                acc1[r] = fmaf(xv[r][kk], wf1[kk], acc1[r]);
            }
    }

    const float bv0 = bb[o0];
    const float bv1 = bb[o0 + 1];
    const float a0 = att[o0];
    const float a1 = att[o0 + 1];
    float* dst = which ? xr : xl;
    float* dp  = which ? dr : dl;
    float dcon[4];
    #pragma unroll
    for (int r = 0; r < 4; ++r) {
        float y0 = acc0[r] + bv0;
        float y1 = acc1[r] + bv1;
        *(float2*)(&dst[(size_t)(row0 + r0 + r) * OD + o0]) = make_float2(y0, y1);
        dcon[r] = fmaf(a0, y0, a1 * y1);
    }
    #pragma unroll
    for (int m = 1; m < 16; m <<= 1) {
        #pragma unroll
        for (int r = 0; r < 4; ++r)
            dcon[r] += __shfl_xor(dcon[r], m);
    }
    if ((og & 15) == 0) {
        const int h = og >> 4;
        #pragma unroll
        for (int r = 0; r < 4; ++r)
            dp[(size_t)(row0 + r0 + r) * H_ + h] = DLR_SCALE * dcon[r];
    }
}

// ---------------------------------------------------------------------------
// Kernel 2: masked-softmax attention aggregate. ZERO LDS, ZERO BARRIERS.
// grid 2048 (= B * N/TI), block 256 -> 8 blocks/CU of grid parallelism;
// occupancy now VGPR-capped only (r10 post-mortem: 33 KB epilogue LDS +
// grid 1024 pinned us at 4 blocks/CU / 21% occupancy).
// thread: cq = t&3 (c-quarter), js = (t>>2)&15 (16 j-slices), h = t>>6.
// All 16 js slices of a head live in ONE wave (lane bits 2-5), so the
// js-reduction is a 4-level shfl_xor reduce-scatter -- no LDS transpose.
// e2: scalar add + fma with folded |.| modifier (2 instr/elem, minimal);
// PV: forced v_pk_fma_f32. Logits in log2 domain -> single v_exp_f32.
// ---------------------------------------------------------------------------
__global__ __launch_bounds__(256, 3) void attn_kernel(
    const int* __restrict__ adj, const float* __restrict__ att,
    const float* __restrict__ bias,
    const float* __restrict__ xl, const float* __restrict__ xr,
    const float* __restrict__ dl, const float* __restrict__ dr,
    float* __restrict__ out)
{
    const int t = threadIdx.x;
    const int b  = blockIdx.x >> 8;
    const int i0 = (blockIdx.x & 255) * TI;
    const int cq = t & 3;
    const int js = (t >> 2) & 15;
    const int h  = t >> 6;
    const int cbase = h * PH + cq * 8;

    float atS[8];
    {
        const float* ap = att + cbase;
        float4 a0 = *(const float4*)(ap);
        float4 a1 = *(const float4*)(ap + 4);
        atS[0] = ATT_SCALE * a0.x; atS[1] = ATT_SCALE * a0.y;
        atS[2] = ATT_SCALE * a0.z; atS[3] = ATT_SCALE * a0.w;
        atS[4] = ATT_SCALE * a1.x; atS[5] = ATT_SCALE * a1.y;
        atS[6] = ATT_SCALE * a1.z; atS[7] = ATT_SCALE * a1.w;
    }
    float xrS[TI][8];
    float drv[TI];
    #pragma unroll
    for (int il = 0; il < TI; ++il) {
        const float* xp = xr + ((size_t)(b * N_ + i0 + il)) * OD + cbase;
        float4 r0 = *(const float4*)(xp);
        float4 r1 = *(const float4*)(xp + 4);
        xrS[il][0] = r0.x; xrS[il][1] = r0.y; xrS[il][2] = r0.z; xrS[il][3] = r0.w;
        xrS[il][4] = r1.x; xrS[il][5] = r1.y; xrS[il][6] = r1.z; xrS[il][7] = r1.w;
        drv[il] = dr[((size_t)(b * N_ + i0 + il)) * H_ + h];  // pre-scaled
    }

    v2f acc[TI][4];
    float sumw[TI];
    #pragma unroll
    for (int il = 0; il < TI; ++il) {
        sumw[il] = 0.f;
        #pragma unroll
        for (int m = 0; m < 4; ++m) acc[il][m] = (v2f){0.f, 0.f};
    }

    // software-pipelined j-loop: j = u*16 + js, u = 0..31
    const float* xlp = xl + ((size_t)(b * N_ + js)) * OD + cbase;
    const int*   ajp = adj + ((size_t)(b * N_ + js)) * N_ + i0;
    const float* dlp = dl + ((size_t)(b * N_ + js)) * H_ + h;

    float4 va = *(const float4*)(xlp);
    float4 vb = *(const float4*)(xlp + 4);
    int2   mj = *(const int2*)(ajp);
    float  dj = *dlp;

    #pragma unroll 2
    for (int u = 0; u < 32; ++u) {
        float4 wa = va, wb = vb;
        int2   wm = mj;
        float  wd = dj;
        if (u < 31) {
            xlp += 16 * OD; ajp += 16 * N_; dlp += 16 * H_;
            va = *(const float4*)(xlp);
            vb = *(const float4*)(xlp + 4);
            mj = *(const int2*)(ajp);
            dj = *dlp;
        }
        const int j = u * 16 + js;
        v2f p0 = (v2f){wa.x, wa.y}, p1 = (v2f){wa.z, wa.w};
        v2f p2 = (v2f){wb.x, wb.y}, p3 = (v2f){wb.z, wb.w};
        int wmv[TI] = {wm.x, wm.y};
        #pragma unroll
        for (int il = 0; il < TI; ++il) {
            float s, e2a = 0.f, e2b = 0.f;
            s = xrS[il][0] + wa.x; e2a = fmaf(atS[0], __builtin_fabsf(s), e2a);
            s = xrS[il][1] + wa.y; e2b = fmaf(atS[1], __builtin_fabsf(s), e2b);
            s = xrS[il][2] + wa.z; e2a = fmaf(atS[2], __builtin_fabsf(s), e2a);
            s = xrS[il][3] + wa.w; e2b = fmaf(atS[3], __builtin_fabsf(s), e2b);
            s = xrS[il][4] + wb.x; e2a = fmaf(atS[4], __builtin_fabsf(s), e2a);
            s = xrS[il][5] + wb.y; e2b = fmaf(atS[5], __builtin_fabsf(s), e2b);
            s = xrS[il][6] + wb.z; e2a = fmaf(atS[6], __builtin_fabsf(s), e2a);
            s = xrS[il][7] + wb.w; e2b = fmaf(atS[7], __builtin_fabsf(s), e2b);
            float eh = e2a + e2b;
            eh = dpp_add<0xB1>(eh);          // + lane^1 (quad_perm 1,0,3,2)
            eh = dpp_add<0x4E>(eh);          // + lane^2 (quad_perm 2,3,0,1)
            float e = (wd + drv[il]) + eh;   // full log2-domain logit
            bool keep = (wmv[il] != 0) || (j == i0 + il);
            float w = keep ? fast_exp2(e) : 0.f;
            sumw[il] += w;
            v2f ws = (v2f){w, w};
            pk_fma(acc[il][0], ws, p0);
            pk_fma(acc[il][1], ws, p1);
            pk_fma(acc[il][2], ws, p2);
            pk_fma(acc[il][3], ws, p3);
        }
    }

    // ---- epilogue: pure-shuffle js-reduction (lane bits 2-5), no LDS ----
    // sumw: full butterfly so every lane has both il sums.
    #pragma unroll
    for (int il = 0; il < TI; ++il) {
        sumw[il] += __shfl_xor(sumw[il], 4);
        sumw[il] += __shfl_xor(sumw[il], 8);
        sumw[il] += __shfl_xor(sumw[il], 16);
        sumw[il] += __shfl_xor(sumw[il], 32);
    }

    float accf[16];
    #pragma unroll
    for (int il = 0; il < TI; ++il)
        #pragma unroll
        for (int m = 0; m < 4; ++m) {
            accf[il * 8 + 2 * m]     = acc[il][m].x;
            accf[il * 8 + 2 * m + 1] = acc[il][m].y;
        }

    // level 0 (xor 4, js bit0): select il
    float r8[8];
    {
        const bool hi = (js & 1) != 0;
        #pragma unroll
        for (int m = 0; m < 8; ++m) {
            float send = hi ? accf[m] : accf[8 + m];
            float keep = hi ? accf[8 + m] : accf[m];
            r8[m] = keep + __shfl_xor(send, 4);
        }
    }
    // level 1 (xor 8, js bit1): halve c (8 -> 4)
    float r4[4];
    {
        const bool hi = (js & 2) != 0;
        #pragma unroll
        for (int m = 0; m < 4; ++m) {
            float send = hi ? r8[m] : r8[4 + m];
            float keep = hi ? r8[4 + m] : r8[m];
            r4[m] = keep + __shfl_xor(send, 8);
        }
    }
    // level 2 (xor 16, js bit2): 4 -> 2
    float r2[2];
    {
        const bool hi = (js & 4) != 0;
        #pragma unroll
        for (int m = 0; m < 2; ++m) {
            float send = hi ? r4[m] : r4[2 + m];
            float keep = hi ? r4[2 + m] : r4[m];
            r2[m] = keep + __shfl_xor(send, 16);
        }
    }
    // level 3 (xor 32, js bit3): 2 -> 1
    float r1;
    {
        const bool hi = (js & 8) != 0;
        float send = hi ? r2[0] : r2[1];
        float keep = hi ? r2[1] : r2[0];
        r1 = keep + __shfl_xor(send, 32);
    }

    const int il = js & 1;
    const int coff = ((js >> 1) & 1) * 4 + ((js >> 2) & 1) * 2 + ((js >> 3) & 1);
    const int c = cbase + coff;
    const float inv = 1.f / sumw[il];
    out[((size_t)(b * N_ + i0 + il)) * OD + c] = fmaf(r1, inv, bias[c]);
}

extern "C" void kernel_launch(void* const* d_in, const int* in_sizes, int n_in,
                              void* d_out, int out_size, void* d_ws, size_t ws_size,
                              hipStream_t stream) {
    const float* x    = (const float*)d_in[0];
    const int*   adj  = (const int*)d_in[1];
    const float* Wl   = (const float*)d_in[2];
    const float* bl   = (const float*)d_in[3];
    const float* Wr   = (const float*)d_in[4];
    const float* br   = (const float*)d_in[5];
    const float* att  = (const float*)d_in[6];
    const float* bias = (const float*)d_in[7];
    float* out = (float*)d_out;

    float* xl = (float*)d_ws;                    // 2 MB
    float* xr = xl + (size_t)B_ * N_ * OD;       // 2 MB
    float* dl = xr + (size_t)B_ * N_ * OD;       // 64 KB
    float* dr = dl + (size_t)B_ * N_ * H_;       // 64 KB

    proj_kernel<<<512, 256, 0, stream>>>(x, Wl, bl, Wr, br, att, xl, xr, dl, dr);
    attn_kernel<<<2048, 256, 0, stream>>>(adj, att, bias, xl, xr, dl, dr, out);
}

// Round 12
// 122.895 us; speedup vs baseline: 1.0608x; 1.0608x over previous
//
#include <hip/hip_runtime.h>
#include <hip/hip_bf16.h>

#define B_   8
#define N_   512
#define IND  256
#define H_   4
#define PH   32
#define OD   128   // H_*PH
#define TI   4     // targets per block (attn)

typedef float v2f __attribute__((ext_vector_type(2)));

// leaky 0.4 * log2(e), and 0.6 * log2(e): logits in log2 domain -> v_exp_f32.
#define ATT_SCALE 0.5770780163555854f
#define DLR_SCALE 0.8656170245333781f

template <int PAT>
__device__ __forceinline__ float dpp_add(float x) {
    int yi = __builtin_amdgcn_mov_dpp(__float_as_int(x), PAT, 0xF, 0xF, true);
    return x + __int_as_float(yi);
}

__device__ __forceinline__ float fast_exp2(float x) {
#if __has_builtin(__builtin_amdgcn_exp2f)
    return __builtin_amdgcn_exp2f(x);
#else
    return exp2f(x);
#endif
}

// Packed fp32 FMA / ADD forced as single VOP3P instructions (r9 post-mortem:
// the compiler scalarizes v2f arithmetic when mixed with modifiers).
__device__ __forceinline__ void pk_fma(v2f& d, v2f a, v2f b) {
    asm("v_pk_fma_f32 %0, %1, %2, %0" : "+v"(d) : "v"(a), "v"(b));
}
__device__ __forceinline__ v2f pk_add(v2f a, v2f b) {
    v2f d;
    asm("v_pk_add_f32 %0, %1, %2" : "=v"(d) : "v"(a), "v"(b));
    return d;
}

// ---------------------------------------------------------------------------
// Kernel 1: xl = x@Wl + bl ; xr = x@Wr + br  plus pre-scaled rank-1 parts
//   dl[n,h] = 0.6*log2e * sum_c att[h,c]*xl[n,h,c]; dr likewise.
// grid 512, block 256; 8 rows per block. (unchanged, proven r5-r11)
// ---------------------------------------------------------------------------
__global__ __launch_bounds__(256, 2) void proj_kernel(
    const float* __restrict__ x,
    const float* __restrict__ Wl, const float* __restrict__ bl,
    const float* __restrict__ Wr, const float* __restrict__ br,
    const float* __restrict__ att,
    float* __restrict__ xl, float* __restrict__ xr,
    float* __restrict__ dl, float* __restrict__ dr)
{
    __shared__ float xs[8 * IND];
    const int t = threadIdx.x;
    const int row0 = blockIdx.x * 8;

    const float4* xp4 = (const float4*)(x + (size_t)row0 * IND);
    float4* xs4 = (float4*)xs;
    #pragma unroll
    for (int k = 0; k < 2; ++k)
        xs4[t + k * 256] = xp4[t + k * 256];
    __syncthreads();

    const int which = t >> 7;
    const int rg = (t >> 6) & 1;
    const int og = t & 63;
    const int o0 = og * 2;
    const int r0 = rg * 4;
    const float* W  = which ? Wr : Wl;
    const float* bb = which ? br : bl;

    float acc0[4], acc1[4];
    #pragma unroll
    for (int r = 0; r < 4; ++r) { acc0[r] = 0.f; acc1[r] = 0.f; }

    for (int k = 0; k < IND; k += 4) {
        float wf0[4], wf1[4];
        #pragma unroll
        for (int kk = 0; kk < 4; ++kk) {
            float2 wv = *(const float2*)(W + (size_t)(k + kk) * OD + o0);
            wf0[kk] = wv.x;
            wf1[kk] = wv.y;
        }
        float xv[4][4];
        #pragma unroll
        for (int r = 0; r < 4; ++r)
            *(float4*)(xv[r]) = *(const float4*)(&xs[(r0 + r) * IND + k]);
        #pragma unroll
        for (int kk = 0; kk < 4; ++kk)
            #pragma unroll
            for (int r = 0; r < 4; ++r) {
                acc0[r] = fmaf(xv[r][kk], wf0[kk], acc0[r]);
                acc1[r] = fmaf(xv[r][kk], wf1[kk], acc1[r]);
            }
    }

    const float bv0 = bb[o0];
    const float bv1 = bb[o0 + 1];
    const float a0 = att[o0];
    const float a1 = att[o0 + 1];
    float* dst = which ? xr : xl;
    float* dp  = which ? dr : dl;
    float dcon[4];
    #pragma unroll
    for (int r = 0; r < 4; ++r) {
        float y0 = acc0[r] + bv0;
        float y1 = acc1[r] + bv1;
        *(float2*)(&dst[(size_t)(row0 + r0 + r) * OD + o0]) = make_float2(y0, y1);
        dcon[r] = fmaf(a0, y0, a1 * y1);
    }
    #pragma unroll
    for (int m = 1; m < 16; m <<= 1) {
        #pragma unroll
        for (int r = 0; r < 4; ++r)
            dcon[r] += __shfl_xor(dcon[r], m);
    }
    if ((og & 15) == 0) {
        const int h = og >> 4;
        #pragma unroll
        for (int r = 0; r < 4; ++r)
            dp[(size_t)(row0 + r0 + r) * H_ + h] = DLR_SCALE * dcon[r];
    }
}

// ---------------------------------------------------------------------------
// Kernel 2: masked-softmax attention aggregate. ZERO LDS, ZERO BARRIERS.
// grid 1024 (= B * N/TI), block 256. TI=4 (r11 lesson: TI=2 doubled loads
// and total instructions; shared xl loads amortize over TI).
// thread: cq = t&3 (c-quarter), js = (t>>2)&15 (16 j-slices), h = t>>6.
// e2: v_pk_add_f32 (forced) + scalar fma with folded |.| = 1.5 instr/elem.
// PV: forced v_pk_fma_f32. Logits in log2 domain -> single v_exp_f32.
// Epilogue: 5-level pure-shuffle reduce-scatter (js bits + il), no LDS.
// ---------------------------------------------------------------------------
__global__ __launch_bounds__(256, 3) void attn_kernel(
    const int* __restrict__ adj, const float* __restrict__ att,
    const float* __restrict__ bias,
    const float* __restrict__ xl, const float* __restrict__ xr,
    const float* __restrict__ dl, const float* __restrict__ dr,
    float* __restrict__ out)
{
    const int t = threadIdx.x;
    const int b  = blockIdx.x >> 7;
    const int i0 = (blockIdx.x & 127) * TI;
    const int cq = t & 3;
    const int js = (t >> 2) & 15;
    const int h  = t >> 6;
    const int cbase = h * PH + cq * 8;

    float atS[8];
    {
        const float* ap = att + cbase;
        float4 a0 = *(const float4*)(ap);
        float4 a1 = *(const float4*)(ap + 4);
        atS[0] = ATT_SCALE * a0.x; atS[1] = ATT_SCALE * a0.y;
        atS[2] = ATT_SCALE * a0.z; atS[3] = ATT_SCALE * a0.w;
        atS[4] = ATT_SCALE * a1.x; atS[5] = ATT_SCALE * a1.y;
        atS[6] = ATT_SCALE * a1.z; atS[7] = ATT_SCALE * a1.w;
    }
    v2f xr2[TI][4];
    float drv[TI];
    #pragma unroll
    for (int il = 0; il < TI; ++il) {
        const float* xp = xr + ((size_t)(b * N_ + i0 + il)) * OD + cbase;
        float4 r0 = *(const float4*)(xp);
        float4 r1 = *(const float4*)(xp + 4);
        xr2[il][0] = (v2f){r0.x, r0.y};
        xr2[il][1] = (v2f){r0.z, r0.w};
        xr2[il][2] = (v2f){r1.x, r1.y};
        xr2[il][3] = (v2f){r1.z, r1.w};
        drv[il] = dr[((size_t)(b * N_ + i0 + il)) * H_ + h];  // pre-scaled
    }

    v2f acc[TI][4];
    float sumw[TI];
    #pragma unroll
    for (int il = 0; il < TI; ++il) {
        sumw[il] = 0.f;
        #pragma unroll
        for (int m = 0; m < 4; ++m) acc[il][m] = (v2f){0.f, 0.f};
    }

    // software-pipelined j-loop: j = u*16 + js, u = 0..31
    const float* xlp = xl + ((size_t)(b * N_ + js)) * OD + cbase;
    const int*   ajp = adj + ((size_t)(b * N_ + js)) * N_ + i0;
    const float* dlp = dl + ((size_t)(b * N_ + js)) * H_ + h;

    float4 va = *(const float4*)(xlp);
    float4 vb = *(const float4*)(xlp + 4);
    int4   mj = *(const int4*)(ajp);
    float  dj = *dlp;

    #pragma unroll 2
    for (int u = 0; u < 32; ++u) {
        float4 wa = va, wb = vb;
        int4   wm = mj;
        float  wd = dj;
        if (u < 31) {
            xlp += 16 * OD; ajp += 16 * N_; dlp += 16 * H_;
            va = *(const float4*)(xlp);
            vb = *(const float4*)(xlp + 4);
            mj = *(const int4*)(ajp);
            dj = *dlp;
        }
        const int j = u * 16 + js;
        v2f p0 = (v2f){wa.x, wa.y}, p1 = (v2f){wa.z, wa.w};
        v2f p2 = (v2f){wb.x, wb.y}, p3 = (v2f){wb.z, wb.w};
        int wmv[TI] = {wm.x, wm.y, wm.z, wm.w};
        #pragma unroll
        for (int il = 0; il < TI; ++il) {
            float e2a = 0.f, e2b = 0.f;
            v2f s;
            s = pk_add(xr2[il][0], p0);
            e2a = fmaf(atS[0], __builtin_fabsf(s.x), e2a);
            e2b = fmaf(atS[1], __builtin_fabsf(s.y), e2b);
            s = pk_add(xr2[il][1], p1);
            e2a = fmaf(atS[2], __builtin_fabsf(s.x), e2a);
            e2b = fmaf(atS[3], __builtin_fabsf(s.y), e2b);
            s = pk_add(xr2[il][2], p2);
            e2a = fmaf(atS[4], __builtin_fabsf(s.x), e2a);
            e2b = fmaf(atS[5], __builtin_fabsf(s.y), e2b);
            s = pk_add(xr2[il][3], p3);
            e2a = fmaf(atS[6], __builtin_fabsf(s.x), e2a);
            e2b = fmaf(atS[7], __builtin_fabsf(s.y), e2b);
            float eh = e2a + e2b;
            eh = dpp_add<0xB1>(eh);          // + lane^1 (quad_perm 1,0,3,2)
            eh = dpp_add<0x4E>(eh);          // + lane^2 (quad_perm 2,3,0,1)
            float e = (wd + drv[il]) + eh;   // full log2-domain logit
            bool keep = (wmv[il] != 0) || (j == i0 + il);
            float w = keep ? fast_exp2(e) : 0.f;
            sumw[il] += w;
            v2f ws = (v2f){w, w};
            pk_fma(acc[il][0], ws, p0);
            pk_fma(acc[il][1], ws, p1);
            pk_fma(acc[il][2], ws, p2);
            pk_fma(acc[il][3], ws, p3);
        }
    }

    // ---- epilogue: pure-shuffle reduce-scatter over js (lane bits 2-5) ----
    // sumw: full butterfly so every lane holds all 4 il sums.
    #pragma unroll
    for (int il = 0; il < TI; ++il) {
        sumw[il] += __shfl_xor(sumw[il], 4);
        sumw[il] += __shfl_xor(sumw[il], 8);
        sumw[il] += __shfl_xor(sumw[il], 16);
        sumw[il] += __shfl_xor(sumw[il], 32);
    }

    float accf[32];
    #pragma unroll
    for (int il = 0; il < TI; ++il)
        #pragma unroll
        for (int m = 0; m < 4; ++m) {
            accf[il * 8 + 2 * m]     = acc[il][m].x;
            accf[il * 8 + 2 * m + 1] = acc[il][m].y;
        }

    // level 0 (xor 4, js bit0): selects il bit1
    float r16[16];
    {
        const bool hi = (js & 1) != 0;
        #pragma unroll
        for (int m = 0; m < 16; ++m) {
            float send = hi ? accf[m] : accf[16 + m];
            float keep = hi ? accf[16 + m] : accf[m];
            r16[m] = keep + __shfl_xor(send, 4);
        }
    }
    // level 1 (xor 8, js bit1): selects il bit0
    float r8[8];
    {
        const bool hi = (js & 2) != 0;
        #pragma unroll
        for (int m = 0; m < 8; ++m) {
            float send = hi ? r16[m] : r16[8 + m];
            float keep = hi ? r16[8 + m] : r16[m];
            r8[m] = keep + __shfl_xor(send, 8);
        }
    }
    // level 2 (xor 16, js bit2): c bit2 (value 4)
    float r4[4];
    {
        const bool hi = (js & 4) != 0;
        #pragma unroll
        for (int m = 0; m < 4; ++m) {
            float send = hi ? r8[m] : r8[4 + m];
            float keep = hi ? r8[4 + m] : r8[m];
            r4[m] = keep + __shfl_xor(send, 16);
        }
    }
    // level 3 (xor 32, js bit3): c bit1 (value 2)
    float r2[2];
    {
        const bool hi = (js & 8) != 0;
        #pragma unroll
        for (int m = 0; m < 2; ++m) {
            float send = hi ? r4[m] : r4[2 + m];
            float keep = hi ? r4[2 + m] : r4[m];
            r2[m] = keep + __shfl_xor(send, 32);
        }
    }

    const int il = ((js & 1) << 1) | ((js >> 1) & 1);
    const int coff = ((js >> 2) & 1) * 4 + ((js >> 3) & 1) * 2;
    const int c = cbase + coff;
    const float sw0 = (js & 1) ? ((js & 2) ? sumw[3] : sumw[2])
                               : ((js & 2) ? sumw[1] : sumw[0]);
    const float inv = 1.f / sw0;
    float* op = out + ((size_t)(b * N_ + i0 + il)) * OD;
    *(float2*)(&op[c]) = make_float2(fmaf(r2[0], inv, bias[c]),
                                     fmaf(r2[1], inv, bias[c + 1]));
}

extern "C" void kernel_launch(void* const* d_in, const int* in_sizes, int n_in,
                              void* d_out, int out_size, void* d_ws, size_t ws_size,
                              hipStream_t stream) {
    const float* x    = (const float*)d_in[0];
    const int*   adj  = (const int*)d_in[1];
    const float* Wl   = (const float*)d_in[2];
    const float* bl   = (const float*)d_in[3];
    const float* Wr   = (const float*)d_in[4];
    const float* br   = (const float*)d_in[5];
    const float* att  = (const float*)d_in[6];
    const float* bias = (const float*)d_in[7];
    float* out = (float*)d_out;

    float* xl = (float*)d_ws;                    // 2 MB
    float* xr = xl + (size_t)B_ * N_ * OD;       // 2 MB
    float* dl = xr + (size_t)B_ * N_ * OD;       // 64 KB
    float* dr = dl + (size_t)B_ * N_ * H_;       // 64 KB

    proj_kernel<<<512, 256, 0, stream>>>(x, Wl, bl, Wr, br, att, xl, xr, dl, dr);
    attn_kernel<<<1024, 256, 0, stream>>>(adj, att, bias, xl, xr, dl, dr, out);
}